// Round 1
// baseline (2565.147 us; speedup 1.0000x reference)
//
#include <hip/hip_runtime.h>

// Problem constants
// B=8, T=1024, DIM=2048, H=16, NKV=4, HD=128, G=4
#define T_SEQ 1024

typedef _Float16 f16x8 __attribute__((ext_vector_type(8)));
typedef float f32x4 __attribute__((ext_vector_type(4)));

// ---------------- fp32 -> fp16 convert (8 elems/thread) ----------------
__global__ __launch_bounds__(256) void f32_to_f16(const float* __restrict__ in,
                                                  _Float16* __restrict__ out, int n8) {
  int i = blockIdx.x * 256 + threadIdx.x;
  if (i >= n8) return;
  const float4* p = (const float4*)in + (size_t)i * 2;
  float4 a = p[0], b = p[1];
  f16x8 o;
  o[0] = (_Float16)a.x; o[1] = (_Float16)a.y; o[2] = (_Float16)a.z; o[3] = (_Float16)a.w;
  o[4] = (_Float16)b.x; o[5] = (_Float16)b.y; o[6] = (_Float16)b.z; o[7] = (_Float16)b.w;
  ((f16x8*)out)[i] = o;
}

// ---------------- f16 MFMA GEMM: C[M,N] = A[M,K] @ B[N,K]^T ----------------
// 64x64 tile, BK=32, 256 threads = 4 waves, wave quadrant 32x32 (2x2 MFMA tiles)
__global__ __launch_bounds__(256) void gemm_f16(const _Float16* __restrict__ A,
                                                const _Float16* __restrict__ B,
                                                float* __restrict__ C,
                                                int K, int N) {
  __shared__ _Float16 As[64][40];  // +8 pad: breaks 16-bank row stride
  __shared__ _Float16 Bs[64][40];
  int tid = threadIdx.x;
  int bm = blockIdx.x, bn = blockIdx.y;
  int wave = tid >> 6, lane = tid & 63;
  int w_m = (wave >> 1) * 32, w_n = (wave & 1) * 32;

  f32x4 zero = {0.f, 0.f, 0.f, 0.f};
  f32x4 acc[2][2] = {{zero, zero}, {zero, zero}};

  int lr = tid >> 2;            // staging row 0..63
  int lc = (tid & 3) * 8;       // staging col group
  const _Float16* Ag = A + (size_t)(bm * 64 + lr) * K + lc;
  const _Float16* Bg = B + (size_t)(bn * 64 + lr) * K + lc;
  int row = lane & 15, kg = (lane >> 4) * 8;

  for (int k0 = 0; k0 < K; k0 += 32) {
    f16x8 av = *(const f16x8*)(Ag + k0);
    f16x8 bv = *(const f16x8*)(Bg + k0);
    *(f16x8*)&As[lr][lc] = av;
    *(f16x8*)&Bs[lr][lc] = bv;
    __syncthreads();
    f16x8 a0 = *(const f16x8*)&As[w_m + row][kg];
    f16x8 a1 = *(const f16x8*)&As[w_m + 16 + row][kg];
    f16x8 b0 = *(const f16x8*)&Bs[w_n + row][kg];
    f16x8 b1 = *(const f16x8*)&Bs[w_n + 16 + row][kg];
    acc[0][0] = __builtin_amdgcn_mfma_f32_16x16x32_f16(a0, b0, acc[0][0], 0, 0, 0);
    acc[0][1] = __builtin_amdgcn_mfma_f32_16x16x32_f16(a0, b1, acc[0][1], 0, 0, 0);
    acc[1][0] = __builtin_amdgcn_mfma_f32_16x16x32_f16(a1, b0, acc[1][0], 0, 0, 0);
    acc[1][1] = __builtin_amdgcn_mfma_f32_16x16x32_f16(a1, b1, acc[1][1], 0, 0, 0);
    __syncthreads();
  }

  // C/D layout: col = lane&15, row = (lane>>4)*4 + r
  int col = lane & 15, rb = (lane >> 4) * 4;
#pragma unroll
  for (int mi = 0; mi < 2; mi++)
#pragma unroll
    for (int ni = 0; ni < 2; ni++) {
      size_t gr = (size_t)(bm * 64 + w_m + mi * 16 + rb);
      int gc = bn * 64 + w_n + ni * 16 + col;
#pragma unroll
      for (int r = 0; r < 4; r++)
        C[(gr + r) * N + gc] = acc[mi][ni][r];
    }
}

// ---------------- RMSNorm + RoPE (+ optional per-head gain), in place ----------------
// one wave per (bt, h) row of 128; lane handles pair (d, d+64)
__global__ __launch_bounds__(256) void rmsrope(float* __restrict__ x,
                                               const float* __restrict__ gain, int nh) {
  int gw = blockIdx.x * 4 + (threadIdx.x >> 6);  // bt*nh + h
  int lane = threadIdx.x & 63;
  int h = gw % nh;
  int t = (gw / nh) % T_SEQ;
  float* row = x + (size_t)gw * 128;
  float x1 = row[lane], x2 = row[lane + 64];
  float ss = x1 * x1 + x2 * x2;
#pragma unroll
  for (int m = 1; m < 64; m <<= 1) ss += __shfl_xor(ss, m);
  float scale = rsqrtf(ss * (1.0f / 128.0f) + 1e-6f);
  if (gain != nullptr) scale *= gain[h];
  // inv[i] = 10000^(-i/64) = 2^(-i*log2(10000)/64)
  float inv = exp2f((float)lane * -0.2076205059304601f);
  float ang = (float)t * inv;
  float c = cosf(ang), s = sinf(ang);
  row[lane]      = (x1 * c - x2 * s) * scale;
  row[lane + 64] = (x2 * c + x1 * s) * scale;
}

// ---------------- fp32 tile-flash GQA causal attention ----------------
// grid (T/32, H, B); block 256. QT=KT=32, HD=128. O kept in registers.
__global__ __launch_bounds__(256) void attn(const float* __restrict__ q,
                                            const float* __restrict__ k,
                                            const float* __restrict__ v,
                                            float* __restrict__ y) {
  __shared__ float Qs[32][132];
  __shared__ float Ks[32][132];
  __shared__ float Vs[32][132];
  __shared__ float Ss[32][33];
  __shared__ float mrow[32], lrow[32], arow[32];
  int qt = blockIdx.x, h = blockIdx.y, b = blockIdx.z;
  int n = h >> 2;  // kv head (G=4)
  int tid = threadIdx.x;

  for (int i = tid; i < 32 * 32; i += 256) {  // 32 rows x 32 float4
    int r = i >> 5, c = (i & 31) * 4;
    *(float4*)&Qs[r][c] =
        *(const float4*)&q[((size_t)(b * T_SEQ + qt * 32 + r) * 16 + h) * 128 + c];
  }
  if (tid < 32) { mrow[tid] = -1e30f; lrow[tid] = 0.f; }

  float O[16];
#pragma unroll
  for (int i = 0; i < 16; i++) O[i] = 0.f;
  int oq = tid >> 3, ob = (tid & 7) * 16;  // PV: row, 16-col slab
  int tr = tid >> 4, tc = tid & 15;        // scores: 16x16 thread grid, 2x2 each
  const float SC = 0.08838834764831845f;   // 128^-0.5

  for (int s0 = 0; s0 < qt * 32 + 32; s0 += 32) {
    __syncthreads();
    for (int i = tid; i < 32 * 32; i += 256) {
      int r = i >> 5, c = (i & 31) * 4;
      size_t base = ((size_t)(b * T_SEQ + s0 + r) * 4 + n) * 128 + c;
      *(float4*)&Ks[r][c] = *(const float4*)&k[base];
      *(float4*)&Vs[r][c] = *(const float4*)&v[base];
    }
    __syncthreads();

    float s00 = 0.f, s01 = 0.f, s10 = 0.f, s11 = 0.f;
#pragma unroll 4
    for (int kk = 0; kk < 128; kk += 4) {
      float4 q0 = *(float4*)&Qs[tr][kk];
      float4 q1 = *(float4*)&Qs[tr + 16][kk];
      float4 k0 = *(float4*)&Ks[tc][kk];
      float4 k1 = *(float4*)&Ks[tc + 16][kk];
      s00 += q0.x * k0.x + q0.y * k0.y + q0.z * k0.z + q0.w * k0.w;
      s01 += q0.x * k1.x + q0.y * k1.y + q0.z * k1.z + q0.w * k1.w;
      s10 += q1.x * k0.x + q1.y * k0.y + q1.z * k0.z + q1.w * k0.w;
      s11 += q1.x * k1.x + q1.y * k1.y + q1.z * k1.z + q1.w * k1.w;
    }
    int t0 = qt * 32 + tr, t1 = t0 + 16;
    int c0 = s0 + tc, c1 = c0 + 16;
    Ss[tr][tc]           = (c0 <= t0) ? s00 * SC : -1e30f;
    Ss[tr][tc + 16]      = (c1 <= t0) ? s01 * SC : -1e30f;
    Ss[tr + 16][tc]      = (c0 <= t1) ? s10 * SC : -1e30f;
    Ss[tr + 16][tc + 16] = (c1 <= t1) ? s11 * SC : -1e30f;
    __syncthreads();

    if (tid < 32) {  // online softmax row update
      float m = mrow[tid], rm = m;
#pragma unroll
      for (int j = 0; j < 32; j++) rm = fmaxf(rm, Ss[tid][j]);
      float a = __expf(m - rm);
      float l = lrow[tid] * a;
#pragma unroll
      for (int j = 0; j < 32; j++) {
        float p = __expf(Ss[tid][j] - rm);
        Ss[tid][j] = p;
        l += p;
      }
      mrow[tid] = rm; lrow[tid] = l; arow[tid] = a;
    }
    __syncthreads();

    float a = arow[oq];
#pragma unroll
    for (int i = 0; i < 16; i++) O[i] *= a;
    for (int si = 0; si < 32; si++) {
      float p = Ss[oq][si];
      float4 v0 = *(float4*)&Vs[si][ob];
      float4 v1 = *(float4*)&Vs[si][ob + 4];
      float4 v2 = *(float4*)&Vs[si][ob + 8];
      float4 v3 = *(float4*)&Vs[si][ob + 12];
      O[0]  += p * v0.x; O[1]  += p * v0.y; O[2]  += p * v0.z; O[3]  += p * v0.w;
      O[4]  += p * v1.x; O[5]  += p * v1.y; O[6]  += p * v1.z; O[7]  += p * v1.w;
      O[8]  += p * v2.x; O[9]  += p * v2.y; O[10] += p * v2.z; O[11] += p * v2.w;
      O[12] += p * v3.x; O[13] += p * v3.y; O[14] += p * v3.z; O[15] += p * v3.w;
    }
  }

  float linv = 1.0f / lrow[oq];
  size_t base = ((size_t)(b * T_SEQ + qt * 32 + oq) * 16 + h) * 128 + ob;
  float4 o;
  o.x = O[0] * linv;  o.y = O[1] * linv;  o.z = O[2] * linv;  o.w = O[3] * linv;
  *(float4*)&y[base] = o;
  o.x = O[4] * linv;  o.y = O[5] * linv;  o.z = O[6] * linv;  o.w = O[7] * linv;
  *(float4*)&y[base + 4] = o;
  o.x = O[8] * linv;  o.y = O[9] * linv;  o.z = O[10] * linv; o.w = O[11] * linv;
  *(float4*)&y[base + 8] = o;
  o.x = O[12] * linv; o.y = O[13] * linv; o.z = O[14] * linv; o.w = O[15] * linv;
  *(float4*)&y[base + 12] = o;
}

// ---------------- v-direction rejection + f16 convert ----------------
// one wave per (bt, n); lane handles (d, d+64)
__global__ __launch_bounds__(256) void vreject(const float* __restrict__ y,
                                               const float* __restrict__ v,
                                               _Float16* __restrict__ yh) {
  int gw = blockIdx.x * 4 + (threadIdx.x >> 6);  // bt*4 + n
  int lane = threadIdx.x & 63;
  int bt = gw >> 2, n = gw & 3;
  const float* vrow = v + (size_t)gw * 128;
  float v1 = vrow[lane], v2 = vrow[lane + 64];
  float ss = v1 * v1 + v2 * v2;
#pragma unroll
  for (int m = 1; m < 64; m <<= 1) ss += __shfl_xor(ss, m);
  float invn = 1.0f / (sqrtf(ss) + 1e-8f);
  float n1 = v1 * invn, n2 = v2 * invn;
  const float* ybase = y + (size_t)bt * 2048 + n * 512;
  _Float16* obase = yh + (size_t)bt * 2048 + n * 512;
#pragma unroll
  for (int g = 0; g < 4; g++) {
    float y1 = ybase[g * 128 + lane], y2 = ybase[g * 128 + lane + 64];
    float d = y1 * n1 + y2 * n2;
#pragma unroll
    for (int m = 1; m < 64; m <<= 1) d += __shfl_xor(d, m);
    obase[g * 128 + lane]      = (_Float16)(y1 - d * n1);
    obase[g * 128 + lane + 64] = (_Float16)(y2 - d * n2);
  }
}

extern "C" void kernel_launch(void* const* d_in, const int* in_sizes, int n_in,
                              void* d_out, int out_size, void* d_ws, size_t ws_size,
                              hipStream_t stream) {
  const float* x    = (const float*)d_in[0];
  const float* Wq   = (const float*)d_in[1];
  const float* Wk   = (const float*)d_in[2];
  const float* Wv   = (const float*)d_in[3];
  const float* Wp   = (const float*)d_in[4];
  const float* gain = (const float*)d_in[5];
  float* out = (float*)d_out;

  // workspace layout (bytes)
  char* w = (char*)d_ws;
  float*     qb  = (float*)(w + 0);           // 8192x2048 f32 = 64 MB
  float*     kb  = (float*)(w + 67108864);    // 8192x512  f32 = 16 MB
  float*     vb  = (float*)(w + 83886080);    // 8192x512  f32 = 16 MB
  _Float16*  xh  = (_Float16*)(w + 100663296); // 8192x2048 f16 = 32 MB
  _Float16*  wqh = (_Float16*)(w + 134217728); // 2048x2048 f16 = 8 MB
  _Float16*  wkh = (_Float16*)(w + 142606336); // 512x2048  f16 = 2 MB
  _Float16*  wvh = (_Float16*)(w + 144703488); // 512x2048  f16 = 2 MB
  _Float16*  wph = (_Float16*)(w + 146800640); // 2048x2048 f16 = 8 MB
  _Float16*  yh  = xh;  // xh dead after QKV GEMMs; reuse for projected-out y

  // 1) convert inputs to f16
  f32_to_f16<<<8192, 256, 0, stream>>>(x, xh, 2097152);
  f32_to_f16<<<2048, 256, 0, stream>>>(Wq, wqh, 524288);
  f32_to_f16<<<512, 256, 0, stream>>>(Wk, wkh, 131072);
  f32_to_f16<<<512, 256, 0, stream>>>(Wv, wvh, 131072);
  f32_to_f16<<<2048, 256, 0, stream>>>(Wp, wph, 524288);

  // 2) QKV projections (MFMA)
  gemm_f16<<<dim3(128, 32), 256, 0, stream>>>(xh, wqh, qb, 2048, 2048);
  gemm_f16<<<dim3(128, 8), 256, 0, stream>>>(xh, wkh, kb, 2048, 512);
  gemm_f16<<<dim3(128, 8), 256, 0, stream>>>(xh, wvh, vb, 2048, 512);

  // 3) RMSNorm + RoPE (q gets gain)
  rmsrope<<<32768, 256, 0, stream>>>(qb, gain, 16);
  rmsrope<<<8192, 256, 0, stream>>>(kb, nullptr, 4);

  // 4) causal GQA attention -> d_out used as fp32 scratch y (b,t,h,d)
  attn<<<dim3(32, 16, 8), 256, 0, stream>>>(qb, kb, vb, out);

  // 5) reject v̂ component, convert to f16
  vreject<<<8192, 256, 0, stream>>>(out, vb, yh);

  // 6) output projection -> final out
  gemm_f16<<<dim3(128, 32), 256, 0, stream>>>(yh, wph, out, 2048, 2048);
}

// Round 2
// 872.345 us; speedup vs baseline: 2.9405x; 2.9405x over previous
//
#include <hip/hip_runtime.h>

// B=8, T=1024, DIM=2048, H=16, NKV=4, HD=128, G=4
#define T_SEQ 1024

typedef _Float16 f16x8 __attribute__((ext_vector_type(8)));
typedef float f32x4 __attribute__((ext_vector_type(4)));

// ---------------- fp32 -> fp16 convert (8 elems/thread) ----------------
__global__ __launch_bounds__(256) void f32_to_f16(const float* __restrict__ in,
                                                  _Float16* __restrict__ out, int n8) {
  int i = blockIdx.x * 256 + threadIdx.x;
  if (i >= n8) return;
  const float4* p = (const float4*)in + (size_t)i * 2;
  float4 a = p[0], b = p[1];
  f16x8 o;
  o[0] = (_Float16)a.x; o[1] = (_Float16)a.y; o[2] = (_Float16)a.z; o[3] = (_Float16)a.w;
  o[4] = (_Float16)b.x; o[5] = (_Float16)b.y; o[6] = (_Float16)b.z; o[7] = (_Float16)b.w;
  ((f16x8*)out)[i] = o;
}

// ---------------- f16 MFMA GEMM: C[M,N] = A[M,K] @ B[N,K]^T ----------------
__global__ __launch_bounds__(256) void gemm_f16(const _Float16* __restrict__ A,
                                                const _Float16* __restrict__ B,
                                                float* __restrict__ C,
                                                int K, int N) {
  __shared__ _Float16 As[64][40];
  __shared__ _Float16 Bs[64][40];
  int tid = threadIdx.x;
  int bm = blockIdx.x, bn = blockIdx.y;
  int wave = tid >> 6, lane = tid & 63;
  int w_m = (wave >> 1) * 32, w_n = (wave & 1) * 32;

  f32x4 zero = {0.f, 0.f, 0.f, 0.f};
  f32x4 acc[2][2] = {{zero, zero}, {zero, zero}};

  int lr = tid >> 2;
  int lc = (tid & 3) * 8;
  const _Float16* Ag = A + (size_t)(bm * 64 + lr) * K + lc;
  const _Float16* Bg = B + (size_t)(bn * 64 + lr) * K + lc;
  int row = lane & 15, kg = (lane >> 4) * 8;

  for (int k0 = 0; k0 < K; k0 += 32) {
    f16x8 av = *(const f16x8*)(Ag + k0);
    f16x8 bv = *(const f16x8*)(Bg + k0);
    *(f16x8*)&As[lr][lc] = av;
    *(f16x8*)&Bs[lr][lc] = bv;
    __syncthreads();
    f16x8 a0 = *(const f16x8*)&As[w_m + row][kg];
    f16x8 a1 = *(const f16x8*)&As[w_m + 16 + row][kg];
    f16x8 b0 = *(const f16x8*)&Bs[w_n + row][kg];
    f16x8 b1 = *(const f16x8*)&Bs[w_n + 16 + row][kg];
    acc[0][0] = __builtin_amdgcn_mfma_f32_16x16x32_f16(a0, b0, acc[0][0], 0, 0, 0);
    acc[0][1] = __builtin_amdgcn_mfma_f32_16x16x32_f16(a0, b1, acc[0][1], 0, 0, 0);
    acc[1][0] = __builtin_amdgcn_mfma_f32_16x16x32_f16(a1, b0, acc[1][0], 0, 0, 0);
    acc[1][1] = __builtin_amdgcn_mfma_f32_16x16x32_f16(a1, b1, acc[1][1], 0, 0, 0);
    __syncthreads();
  }

  int col = lane & 15, rb = (lane >> 4) * 4;
#pragma unroll
  for (int mi = 0; mi < 2; mi++)
#pragma unroll
    for (int ni = 0; ni < 2; ni++) {
      size_t gr = (size_t)(bm * 64 + w_m + mi * 16 + rb);
      int gc = bn * 64 + w_n + ni * 16 + col;
#pragma unroll
      for (int r = 0; r < 4; r++)
        C[(gr + r) * N + gc] = acc[mi][ni][r];
    }
}

// ---------------- RMSNorm + RoPE (+gain), fp32 in -> f16 in place ----------------
// one wave per row of 128; writes 128 f16 into the first 256B of the row slot.
// Safe: data-dependent stores can't be hoisted above the one load instruction,
// and each row is touched by exactly one wave.
__global__ __launch_bounds__(256) void rmsrope_f16(float* __restrict__ x,
                                                   const float* __restrict__ gain, int nh) {
  int gw = blockIdx.x * 4 + (threadIdx.x >> 6);  // bt*nh + h
  int lane = threadIdx.x & 63;
  int h = gw % nh;
  int t = (gw / nh) % T_SEQ;
  float* row = x + (size_t)gw * 128;
  float x1 = row[lane], x2 = row[lane + 64];
  float ss = x1 * x1 + x2 * x2;
#pragma unroll
  for (int m = 1; m < 64; m <<= 1) ss += __shfl_xor(ss, m);
  float scale = rsqrtf(ss * (1.0f / 128.0f) + 1e-6f);
  if (gain != nullptr) scale *= gain[h];
  float inv = exp2f((float)lane * -0.2076205059304601f);  // 10000^(-lane/64)
  float ang = (float)t * inv;
  float c = cosf(ang), s = sinf(ang);
  _Float16* o = (_Float16*)row;
  o[lane]      = (_Float16)((x1 * c - x2 * s) * scale);
  o[lane + 64] = (_Float16)((x2 * c + x1 * s) * scale);
}

// ---------------- f16 MFMA flash attention (causal GQA) ----------------
// grid (T/64, H, B); 4 waves; wave owns 16 Q rows; K/V tile = 64.
// q,k: f16 rows of 128 at stride 256 (converted-in-place buffers)
// v: dense f16 [B*T*NKV][128]; y: fp32 [b,t,h,d]
__global__ __launch_bounds__(256) void attn_mfma(const _Float16* __restrict__ q,
                                                 const _Float16* __restrict__ k,
                                                 const _Float16* __restrict__ v,
                                                 float* __restrict__ y) {
  __shared__ _Float16 Ks[64][136];   // row-major K tile (+8 pad)
  __shared__ _Float16 VT[128][66];   // transposed V tile (stride 66: clean frag reads)
  __shared__ _Float16 Ps[4][16][72]; // per-wave P tile for C->A layout round-trip
  int qt = blockIdx.x, h = blockIdx.y, b = blockIdx.z;
  int kvh = h >> 2;
  int tid = threadIdx.x, wave = tid >> 6, lane = tid & 63;
  int lm = lane & 15, lq = lane >> 4;

  // Q fragments (A-layout: m=lane&15, k=(lane>>4)*8+j), kept in registers
  const _Float16* qp =
      q + (size_t)((b * T_SEQ + qt * 64 + wave * 16 + lm) * 16 + h) * 256 + lq * 8;
  f16x8 qf[4];
#pragma unroll
  for (int i = 0; i < 4; i++) qf[i] = *(const f16x8*)(qp + i * 32);

  f32x4 O[8];
#pragma unroll
  for (int i = 0; i < 8; i++) O[i] = (f32x4){0.f, 0.f, 0.f, 0.f};
  float mrow[4] = {-1e30f, -1e30f, -1e30f, -1e30f};
  float lrow[4] = {0.f, 0.f, 0.f, 0.f};

  int srow = tid >> 4;        // staging row 0..15 (+16i)
  int scol = (tid & 15) * 8;  // staging col group
  const float SC = 0.08838834764831845f;
  int qrow_base = qt * 64 + wave * 16 + lq * 4;

  for (int s0 = 0; s0 <= qt * 64; s0 += 64) {
#pragma unroll
    for (int i = 0; i < 4; i++) {
      int r = i * 16 + srow;
      size_t kr = (size_t)(b * T_SEQ + s0 + r) * 4 + kvh;
      *(f16x8*)&Ks[r][scol] = *(const f16x8*)(k + kr * 256 + scol);
      f16x8 vv = *(const f16x8*)(v + kr * 128 + scol);
#pragma unroll
      for (int j = 0; j < 8; j++) VT[scol + j][r] = vv[j];
    }
    __syncthreads();

    // S = Q K^T (16x64 per wave), K frag = B-layout read straight from Ks
    f32x4 S[4];
#pragma unroll
    for (int ct = 0; ct < 4; ct++) {
      S[ct] = (f32x4){0.f, 0.f, 0.f, 0.f};
#pragma unroll
      for (int ks = 0; ks < 4; ks++) {
        f16x8 bf = *(const f16x8*)&Ks[ct * 16 + lm][ks * 32 + lq * 8];
        S[ct] = __builtin_amdgcn_mfma_f32_16x16x32_f16(qf[ks], bf, S[ct], 0, 0, 0);
      }
    }

    // mask + scale + online softmax; C-layout rows = lq*4+r, cols = ct*16+lm
    float p[4][4];
    float al[4];
#pragma unroll
    for (int r = 0; r < 4; r++) {
      int grow = qrow_base + r;
      float mx = -1e30f;
#pragma unroll
      for (int ct = 0; ct < 4; ct++) {
        float sv = S[ct][r] * SC;
        if (s0 + ct * 16 + lm > grow) sv = -1e30f;
        p[r][ct] = sv;
        mx = fmaxf(mx, sv);
      }
#pragma unroll
      for (int m = 1; m < 16; m <<= 1) mx = fmaxf(mx, __shfl_xor(mx, m));
      float mn = fmaxf(mrow[r], mx);
      float a = __expf(mrow[r] - mn);
      mrow[r] = mn;
      float rs = 0.f;
#pragma unroll
      for (int ct = 0; ct < 4; ct++) {
        float pv = __expf(p[r][ct] - mn);
        p[r][ct] = pv;
        rs += pv;
      }
#pragma unroll
      for (int m = 1; m < 16; m <<= 1) rs += __shfl_xor(rs, m);
      lrow[r] = lrow[r] * a + rs;
      al[r] = a;
    }

    // P -> LDS (C-layout write), rescale O
#pragma unroll
    for (int r = 0; r < 4; r++)
#pragma unroll
      for (int ct = 0; ct < 4; ct++)
        Ps[wave][lq * 4 + r][ct * 16 + lm] = (_Float16)p[r][ct];
#pragma unroll
    for (int ct = 0; ct < 8; ct++)
#pragma unroll
      for (int r = 0; r < 4; r++) O[ct][r] *= al[r];

    // O += P V   (A-frag of P from LDS, B-frag of V from VT; same-wave DS is in-order)
#pragma unroll
    for (int ks = 0; ks < 2; ks++) {
      f16x8 af = *(const f16x8*)&Ps[wave][lm][ks * 32 + lq * 8];
#pragma unroll
      for (int ct = 0; ct < 8; ct++) {
        f16x8 bf = *(const f16x8*)&VT[ct * 16 + lm][ks * 32 + lq * 8];
        O[ct] = __builtin_amdgcn_mfma_f32_16x16x32_f16(af, bf, O[ct], 0, 0, 0);
      }
    }
    __syncthreads();
  }

  float linv[4];
#pragma unroll
  for (int r = 0; r < 4; r++) linv[r] = 1.0f / lrow[r];
#pragma unroll
  for (int ct = 0; ct < 8; ct++)
#pragma unroll
    for (int r = 0; r < 4; r++)
      y[((size_t)(b * T_SEQ + qrow_base + r) * 16 + h) * 128 + ct * 16 + lm] =
          O[ct][r] * linv[r];
}

// ---------------- v-direction rejection + f16 convert ----------------
__global__ __launch_bounds__(256) void vreject(const float* __restrict__ y,
                                               const float* __restrict__ v,
                                               _Float16* __restrict__ yh) {
  int gw = blockIdx.x * 4 + (threadIdx.x >> 6);  // bt*4 + n
  int lane = threadIdx.x & 63;
  int bt = gw >> 2, n = gw & 3;
  const float* vrow = v + (size_t)gw * 128;
  float v1 = vrow[lane], v2 = vrow[lane + 64];
  float ss = v1 * v1 + v2 * v2;
#pragma unroll
  for (int m = 1; m < 64; m <<= 1) ss += __shfl_xor(ss, m);
  float invn = 1.0f / (sqrtf(ss) + 1e-8f);
  float n1 = v1 * invn, n2 = v2 * invn;
  const float* ybase = y + (size_t)bt * 2048 + n * 512;
  _Float16* obase = yh + (size_t)bt * 2048 + n * 512;
#pragma unroll
  for (int g = 0; g < 4; g++) {
    float y1 = ybase[g * 128 + lane], y2 = ybase[g * 128 + lane + 64];
    float d = y1 * n1 + y2 * n2;
#pragma unroll
    for (int m = 1; m < 64; m <<= 1) d += __shfl_xor(d, m);
    obase[g * 128 + lane]      = (_Float16)(y1 - d * n1);
    obase[g * 128 + lane + 64] = (_Float16)(y2 - d * n2);
  }
}

extern "C" void kernel_launch(void* const* d_in, const int* in_sizes, int n_in,
                              void* d_out, int out_size, void* d_ws, size_t ws_size,
                              hipStream_t stream) {
  const float* x    = (const float*)d_in[0];
  const float* Wq   = (const float*)d_in[1];
  const float* Wk   = (const float*)d_in[2];
  const float* Wv   = (const float*)d_in[3];
  const float* Wp   = (const float*)d_in[4];
  const float* gain = (const float*)d_in[5];
  float* out = (float*)d_out;

  // workspace layout (bytes)
  char* w = (char*)d_ws;
  float*     qb  = (float*)(w + 0);            // 8192x2048 f32 = 64 MB
  float*     kb  = (float*)(w + 67108864);     // 8192x512  f32 = 16 MB
  float*     vb  = (float*)(w + 83886080);     // 8192x512  f32 = 16 MB
  _Float16*  xh  = (_Float16*)(w + 100663296); // 8192x2048 f16 = 32 MB
  _Float16*  wqh = (_Float16*)(w + 134217728); // 2048x2048 f16 = 8 MB
  _Float16*  wkh = (_Float16*)(w + 142606336); // 512x2048  f16 = 2 MB
  _Float16*  wvh = (_Float16*)(w + 144703488); // 512x2048  f16 = 2 MB
  _Float16*  wph = (_Float16*)(w + 146800640); // 2048x2048 f16 = 8 MB
  _Float16*  vh  = xh;   // xh dead after QKV GEMMs; v f16 for attention (8 MB)
  _Float16*  yh  = xh;   // vh dead after attention; vreject output (32 MB)

  // 1) convert inputs to f16
  f32_to_f16<<<8192, 256, 0, stream>>>(x, xh, 2097152);
  f32_to_f16<<<2048, 256, 0, stream>>>(Wq, wqh, 524288);
  f32_to_f16<<<512, 256, 0, stream>>>(Wk, wkh, 131072);
  f32_to_f16<<<512, 256, 0, stream>>>(Wv, wvh, 131072);
  f32_to_f16<<<2048, 256, 0, stream>>>(Wp, wph, 524288);

  // 2) QKV projections (MFMA)
  gemm_f16<<<dim3(128, 32), 256, 0, stream>>>(xh, wqh, qb, 2048, 2048);
  gemm_f16<<<dim3(128, 8), 256, 0, stream>>>(xh, wkh, kb, 2048, 512);
  gemm_f16<<<dim3(128, 8), 256, 0, stream>>>(xh, wvh, vb, 2048, 512);

  // 3) RMSNorm + RoPE -> f16 in place (q gets gain); convert v -> f16
  rmsrope_f16<<<32768, 256, 0, stream>>>(qb, gain, 16);
  rmsrope_f16<<<8192, 256, 0, stream>>>(kb, nullptr, 4);
  f32_to_f16<<<2048, 256, 0, stream>>>(vb, vh, 524288);

  // 4) causal GQA MFMA flash attention -> d_out as fp32 y (b,t,h,d)
  attn_mfma<<<dim3(16, 16, 8), 256, 0, stream>>>(
      (const _Float16*)qb, (const _Float16*)kb, vh, out);

  // 5) reject v̂ component, convert to f16
  vreject<<<8192, 256, 0, stream>>>(out, vb, yh);

  // 6) output projection -> final out
  gemm_f16<<<dim3(128, 32), 256, 0, stream>>>(yh, wph, out, 2048, 2048);
}

// Round 3
// 746.981 us; speedup vs baseline: 3.4340x; 1.1678x over previous
//
#include <hip/hip_runtime.h>
#include <stdint.h>

// B=8, T=1024, DIM=2048, H=16, NKV=4, HD=128, G=4
#define T_SEQ 1024

typedef _Float16 f16x8 __attribute__((ext_vector_type(8)));
typedef float f32x4 __attribute__((ext_vector_type(4)));

typedef __attribute__((address_space(1))) const uint8_t* gptr_t;
typedef __attribute__((address_space(3))) uint8_t* lptr_t;

__device__ __forceinline__ void gload16(const _Float16* g, _Float16* l) {
  // async global->LDS DMA, 16B/lane; LDS dest = wave-uniform base + lane*16
  __builtin_amdgcn_global_load_lds((gptr_t)g, (lptr_t)l, 16, 0, 0);
}

// ---------------- fp32 -> fp16 convert (8 elems/thread) ----------------
__global__ __launch_bounds__(256) void f32_to_f16(const float* __restrict__ in,
                                                  _Float16* __restrict__ out, int n8) {
  int i = blockIdx.x * 256 + threadIdx.x;
  if (i >= n8) return;
  const float4* p = (const float4*)in + (size_t)i * 2;
  float4 a = p[0], b = p[1];
  f16x8 o;
  o[0] = (_Float16)a.x; o[1] = (_Float16)a.y; o[2] = (_Float16)a.z; o[3] = (_Float16)a.w;
  o[4] = (_Float16)b.x; o[5] = (_Float16)b.y; o[6] = (_Float16)b.z; o[7] = (_Float16)b.w;
  ((f16x8*)out)[i] = o;
}

// ---------------- m97-style f16 MFMA GEMM: C[M,N] = A[M,K] @ B[N,K]^T ----------------
// 128x128 tile, BK=32, 4 waves, each wave a 64x64 quadrant (4x4 of 16x16x32 MFMA).
// Staging via global_load_lds width=16 (2 instr per 64-row half per operand).
template <typename OutT>
__global__ __launch_bounds__(256) void gemm128(const _Float16* __restrict__ A,
                                               const _Float16* __restrict__ B,
                                               OutT* __restrict__ C,
                                               int K, int N) {
  __shared__ _Float16 As[128][32];  // NO padding: global_load_lds needs dense lane order
  __shared__ _Float16 Bs[128][32];
  int tid = threadIdx.x;
  int bm = blockIdx.x, bn = blockIdx.y;
  int wave = tid >> 6, lane = tid & 63;
  int w_m = (wave >> 1) * 64, w_n = (wave & 1) * 64;
  int lm = lane & 15, lq = lane >> 4;

  f32x4 acc[4][4];
#pragma unroll
  for (int mi = 0; mi < 4; mi++)
#pragma unroll
    for (int ni = 0; ni < 4; ni++) acc[mi][ni] = (f32x4){0.f, 0.f, 0.f, 0.f};

  int sr = tid >> 2;            // staging row 0..63 (first half)
  int sc = (tid & 3) * 8;       // staging col group
  const _Float16* Ag0 = A + (size_t)(bm * 128 + sr) * K + sc;
  const _Float16* Ag1 = Ag0 + (size_t)64 * K;
  const _Float16* Bg0 = B + (size_t)(bn * 128 + sr) * K + sc;
  const _Float16* Bg1 = Bg0 + (size_t)64 * K;
  _Float16* lA0 = &As[wave * 16][0];       // wave-uniform LDS bases
  _Float16* lA1 = &As[64 + wave * 16][0];
  _Float16* lB0 = &Bs[wave * 16][0];
  _Float16* lB1 = &Bs[64 + wave * 16][0];

  for (int k0 = 0; k0 < K; k0 += 32) {
    gload16(Ag0 + k0, lA0);
    gload16(Ag1 + k0, lA1);
    gload16(Bg0 + k0, lB0);
    gload16(Bg1 + k0, lB1);
    __syncthreads();  // drains vmcnt for the DMA

    f16x8 af[4], bf[4];
#pragma unroll
    for (int i = 0; i < 4; i++) af[i] = *(const f16x8*)&As[w_m + i * 16 + lm][lq * 8];
#pragma unroll
    for (int i = 0; i < 4; i++) bf[i] = *(const f16x8*)&Bs[w_n + i * 16 + lm][lq * 8];
#pragma unroll
    for (int mi = 0; mi < 4; mi++)
#pragma unroll
      for (int ni = 0; ni < 4; ni++)
        acc[mi][ni] =
            __builtin_amdgcn_mfma_f32_16x16x32_f16(af[mi], bf[ni], acc[mi][ni], 0, 0, 0);
    __syncthreads();
  }

  // C/D layout: col = lane&15, row = (lane>>4)*4 + r
  int rb = lq * 4;
#pragma unroll
  for (int mi = 0; mi < 4; mi++)
#pragma unroll
    for (int ni = 0; ni < 4; ni++) {
      size_t gr = (size_t)(bm * 128 + w_m + mi * 16 + rb);
      int gc = bn * 128 + w_n + ni * 16 + lm;
#pragma unroll
      for (int r = 0; r < 4; r++)
        C[(gr + r) * N + gc] = (OutT)acc[mi][ni][r];
    }
}

// ---------------- RMSNorm + RoPE (+gain), f16 in place ----------------
// one wave per dense row of 128 f16
__global__ __launch_bounds__(256) void rmsrope16(_Float16* __restrict__ x,
                                                 const float* __restrict__ gain, int nh) {
  int gw = blockIdx.x * 4 + (threadIdx.x >> 6);  // bt*nh + h
  int lane = threadIdx.x & 63;
  int h = gw % nh;
  int t = (gw / nh) % T_SEQ;
  _Float16* row = x + (size_t)gw * 128;
  float x1 = (float)row[lane], x2 = (float)row[lane + 64];
  float ss = x1 * x1 + x2 * x2;
#pragma unroll
  for (int m = 1; m < 64; m <<= 1) ss += __shfl_xor(ss, m);
  float scale = rsqrtf(ss * (1.0f / 128.0f) + 1e-6f);
  if (gain != nullptr) scale *= gain[h];
  float inv = exp2f((float)lane * -0.2076205059304601f);  // 10000^(-lane/64)
  float ang = (float)t * inv;
  float c = cosf(ang), s = sinf(ang);
  row[lane]      = (_Float16)((x1 * c - x2 * s) * scale);
  row[lane + 64] = (_Float16)((x2 * c + x1 * s) * scale);
}

// ---------------- f16 MFMA flash attention (causal GQA) ----------------
// grid (T/64, H, B); 4 waves; wave owns 16 Q rows; K/V tile = 64.
// q: dense f16 [B*T*H][128]; k,v: dense f16 [B*T*NKV][128]; y: fp32 (b,t,h,d)
__global__ __launch_bounds__(256) void attn_mfma(const _Float16* __restrict__ q,
                                                 const _Float16* __restrict__ k,
                                                 const _Float16* __restrict__ v,
                                                 float* __restrict__ y) {
  __shared__ _Float16 Ks[64][136];   // row-major K tile (+8 pad)
  __shared__ _Float16 VT[128][66];   // transposed V tile
  __shared__ _Float16 Ps[4][16][72]; // per-wave P tile for C->A layout round-trip
  int qt = blockIdx.x, h = blockIdx.y, b = blockIdx.z;
  int kvh = h >> 2;
  int tid = threadIdx.x, wave = tid >> 6, lane = tid & 63;
  int lm = lane & 15, lq = lane >> 4;

  const _Float16* qp =
      q + (size_t)((b * T_SEQ + qt * 64 + wave * 16 + lm) * 16 + h) * 128 + lq * 8;
  f16x8 qf[4];
#pragma unroll
  for (int i = 0; i < 4; i++) qf[i] = *(const f16x8*)(qp + i * 32);

  f32x4 O[8];
#pragma unroll
  for (int i = 0; i < 8; i++) O[i] = (f32x4){0.f, 0.f, 0.f, 0.f};
  float mrow[4] = {-1e30f, -1e30f, -1e30f, -1e30f};
  float lrow[4] = {0.f, 0.f, 0.f, 0.f};

  int srow = tid >> 4;        // staging row 0..15 (+16i)
  int scol = (tid & 15) * 8;  // staging col group
  const float SC = 0.08838834764831845f;
  int qrow_base = qt * 64 + wave * 16 + lq * 4;

  for (int s0 = 0; s0 <= qt * 64; s0 += 64) {
#pragma unroll
    for (int i = 0; i < 4; i++) {
      int r = i * 16 + srow;
      size_t kr = (size_t)(b * T_SEQ + s0 + r) * 4 + kvh;
      *(f16x8*)&Ks[r][scol] = *(const f16x8*)(k + kr * 128 + scol);
      f16x8 vv = *(const f16x8*)(v + kr * 128 + scol);
#pragma unroll
      for (int j = 0; j < 8; j++) VT[scol + j][r] = vv[j];
    }
    __syncthreads();

    // S = Q K^T (16x64 per wave)
    f32x4 S[4];
#pragma unroll
    for (int ct = 0; ct < 4; ct++) {
      S[ct] = (f32x4){0.f, 0.f, 0.f, 0.f};
#pragma unroll
      for (int ks = 0; ks < 4; ks++) {
        f16x8 bf = *(const f16x8*)&Ks[ct * 16 + lm][ks * 32 + lq * 8];
        S[ct] = __builtin_amdgcn_mfma_f32_16x16x32_f16(qf[ks], bf, S[ct], 0, 0, 0);
      }
    }

    // mask + scale + online softmax; C-layout rows = lq*4+r, cols = ct*16+lm
    float p[4][4];
    float al[4];
#pragma unroll
    for (int r = 0; r < 4; r++) {
      int grow = qrow_base + r;
      float mx = -1e30f;
#pragma unroll
      for (int ct = 0; ct < 4; ct++) {
        float sv = S[ct][r] * SC;
        if (s0 + ct * 16 + lm > grow) sv = -1e30f;
        p[r][ct] = sv;
        mx = fmaxf(mx, sv);
      }
#pragma unroll
      for (int m = 1; m < 16; m <<= 1) mx = fmaxf(mx, __shfl_xor(mx, m));
      float mn = fmaxf(mrow[r], mx);
      float a = __expf(mrow[r] - mn);
      mrow[r] = mn;
      float rs = 0.f;
#pragma unroll
      for (int ct = 0; ct < 4; ct++) {
        float pv = __expf(p[r][ct] - mn);
        p[r][ct] = pv;
        rs += pv;
      }
#pragma unroll
      for (int m = 1; m < 16; m <<= 1) rs += __shfl_xor(rs, m);
      lrow[r] = lrow[r] * a + rs;
      al[r] = a;
    }

#pragma unroll
    for (int r = 0; r < 4; r++)
#pragma unroll
      for (int ct = 0; ct < 4; ct++)
        Ps[wave][lq * 4 + r][ct * 16 + lm] = (_Float16)p[r][ct];
#pragma unroll
    for (int ct = 0; ct < 8; ct++)
#pragma unroll
      for (int r = 0; r < 4; r++) O[ct][r] *= al[r];

    // O += P V
#pragma unroll
    for (int ks = 0; ks < 2; ks++) {
      f16x8 af = *(const f16x8*)&Ps[wave][lm][ks * 32 + lq * 8];
#pragma unroll
      for (int ct = 0; ct < 8; ct++) {
        f16x8 bf = *(const f16x8*)&VT[ct * 16 + lm][ks * 32 + lq * 8];
        O[ct] = __builtin_amdgcn_mfma_f32_16x16x32_f16(af, bf, O[ct], 0, 0, 0);
      }
    }
    __syncthreads();
  }

  float linv[4];
#pragma unroll
  for (int r = 0; r < 4; r++) linv[r] = 1.0f / lrow[r];
#pragma unroll
  for (int ct = 0; ct < 8; ct++)
#pragma unroll
    for (int r = 0; r < 4; r++)
      y[((size_t)(b * T_SEQ + qrow_base + r) * 16 + h) * 128 + ct * 16 + lm] =
          O[ct][r] * linv[r];
}

// ---------------- v-direction rejection + f16 convert ----------------
__global__ __launch_bounds__(256) void vreject(const float* __restrict__ y,
                                               const _Float16* __restrict__ v,
                                               _Float16* __restrict__ yh) {
  int gw = blockIdx.x * 4 + (threadIdx.x >> 6);  // bt*4 + n
  int lane = threadIdx.x & 63;
  int bt = gw >> 2, n = gw & 3;
  const _Float16* vrow = v + (size_t)gw * 128;
  float v1 = (float)vrow[lane], v2 = (float)vrow[lane + 64];
  float ss = v1 * v1 + v2 * v2;
#pragma unroll
  for (int m = 1; m < 64; m <<= 1) ss += __shfl_xor(ss, m);
  float invn = 1.0f / (sqrtf(ss) + 1e-8f);
  float n1 = v1 * invn, n2 = v2 * invn;
  const float* ybase = y + (size_t)bt * 2048 + n * 512;
  _Float16* obase = yh + (size_t)bt * 2048 + n * 512;
#pragma unroll
  for (int g = 0; g < 4; g++) {
    float y1 = ybase[g * 128 + lane], y2 = ybase[g * 128 + lane + 64];
    float d = y1 * n1 + y2 * n2;
#pragma unroll
    for (int m = 1; m < 64; m <<= 1) d += __shfl_xor(d, m);
    obase[g * 128 + lane]      = (_Float16)(y1 - d * n1);
    obase[g * 128 + lane + 64] = (_Float16)(y2 - d * n2);
  }
}

extern "C" void kernel_launch(void* const* d_in, const int* in_sizes, int n_in,
                              void* d_out, int out_size, void* d_ws, size_t ws_size,
                              hipStream_t stream) {
  const float* x    = (const float*)d_in[0];
  const float* Wq   = (const float*)d_in[1];
  const float* Wk   = (const float*)d_in[2];
  const float* Wv   = (const float*)d_in[3];
  const float* Wp   = (const float*)d_in[4];
  const float* gain = (const float*)d_in[5];
  float* out = (float*)d_out;

  // workspace layout (bytes)
  char* w = (char*)d_ws;
  _Float16* xh  = (_Float16*)(w + 0);         // 8192x2048 f16 = 32 MB
  _Float16* wqh = (_Float16*)(w + 33554432);  // 8 MB
  _Float16* wkh = (_Float16*)(w + 41943040);  // 2 MB
  _Float16* wvh = (_Float16*)(w + 44040192);  // 2 MB
  _Float16* wph = (_Float16*)(w + 46137344);  // 8 MB
  _Float16* qh  = (_Float16*)(w + 54525952);  // 8192x2048 f16 = 32 MB
  _Float16* kh  = (_Float16*)(w + 88080384);  // 8192x512 f16 = 8 MB
  _Float16* vh  = (_Float16*)(w + 96468992);  // 8192x512 f16 = 8 MB
  _Float16* yh  = xh;  // xh dead after QKV GEMMs; vreject output

  // 1) convert inputs to f16
  f32_to_f16<<<8192, 256, 0, stream>>>(x, xh, 2097152);
  f32_to_f16<<<2048, 256, 0, stream>>>(Wq, wqh, 524288);
  f32_to_f16<<<512, 256, 0, stream>>>(Wk, wkh, 131072);
  f32_to_f16<<<512, 256, 0, stream>>>(Wv, wvh, 131072);
  f32_to_f16<<<2048, 256, 0, stream>>>(Wp, wph, 524288);

  // 2) QKV projections (MFMA, f16 out)
  gemm128<_Float16><<<dim3(64, 16), 256, 0, stream>>>(xh, wqh, qh, 2048, 2048);
  gemm128<_Float16><<<dim3(64, 4), 256, 0, stream>>>(xh, wkh, kh, 2048, 512);
  gemm128<_Float16><<<dim3(64, 4), 256, 0, stream>>>(xh, wvh, vh, 2048, 512);

  // 3) RMSNorm + RoPE in place (q gets gain)
  rmsrope16<<<32768, 256, 0, stream>>>(qh, gain, 16);
  rmsrope16<<<8192, 256, 0, stream>>>(kh, nullptr, 4);

  // 4) causal GQA MFMA flash attention -> d_out as fp32 y (b,t,h,d)
  attn_mfma<<<dim3(16, 16, 8), 256, 0, stream>>>(qh, kh, vh, out);

  // 5) reject v̂ component, convert to f16
  vreject<<<8192, 256, 0, stream>>>(out, vh, yh);

  // 6) output projection -> final out (f32)
  gemm128<float><<<dim3(64, 16), 256, 0, stream>>>(yh, wph, out, 2048, 2048);
}

// Round 5
// 646.991 us; speedup vs baseline: 3.9647x; 1.1545x over previous
//
#include <hip/hip_runtime.h>
#include <stdint.h>

// B=8, T=1024, DIM=2048, H=16, NKV=4, HD=128, G=4
#define T_SEQ 1024

typedef _Float16 f16x8 __attribute__((ext_vector_type(8)));
typedef float f32x4 __attribute__((ext_vector_type(4)));

typedef __attribute__((address_space(1))) const uint8_t* gptr_t;
typedef __attribute__((address_space(3))) uint8_t* lptr_t;

__device__ __forceinline__ void gload16(const _Float16* g, _Float16* l) {
  // async global->LDS DMA, 16B/lane; LDS dest = wave-uniform base + lane*16
  __builtin_amdgcn_global_load_lds((gptr_t)g, (lptr_t)l, 16, 0, 0);
}

// ---------------- all five fp32->fp16 converts in one kernel ----------------
__global__ __launch_bounds__(256) void convert_all(
    const float* __restrict__ x, const float* __restrict__ Wq,
    const float* __restrict__ Wk, const float* __restrict__ Wv,
    const float* __restrict__ Wp, _Float16* __restrict__ xh,
    _Float16* __restrict__ wqh, _Float16* __restrict__ wkh,
    _Float16* __restrict__ wvh, _Float16* __restrict__ wph) {
  int i = blockIdx.x * 256 + threadIdx.x;  // vec8 index, total 3407872
  const float* in;
  _Float16* out;
  int base;
  if (i < 2097152)      { in = x;  out = xh;  base = 0; }
  else if (i < 2621440) { in = Wq; out = wqh; base = 2097152; }
  else if (i < 2752512) { in = Wk; out = wkh; base = 2621440; }
  else if (i < 2883584) { in = Wv; out = wvh; base = 2752512; }
  else                  { in = Wp; out = wph; base = 2883584; }
  int j = i - base;
  const float4* p = (const float4*)in + (size_t)j * 2;
  float4 a = p[0], b = p[1];
  f16x8 o;
  o[0] = (_Float16)a.x; o[1] = (_Float16)a.y; o[2] = (_Float16)a.z; o[3] = (_Float16)a.w;
  o[4] = (_Float16)b.x; o[5] = (_Float16)b.y; o[6] = (_Float16)b.z; o[7] = (_Float16)b.w;
  ((f16x8*)out)[j] = o;
}

// ---------------- m97-style f16 MFMA GEMM: C[M,N] = A[M,K] @ B[N,K]^T ----------------
template <typename OutT>
__global__ __launch_bounds__(256) void gemm128(const _Float16* __restrict__ A,
                                               const _Float16* __restrict__ B,
                                               OutT* __restrict__ C,
                                               int K, int N) {
  __shared__ _Float16 As[128][32];  // dense: global_load_lds lane order
  __shared__ _Float16 Bs[128][32];
  int tid = threadIdx.x;
  int bm = blockIdx.x, bn = blockIdx.y;
  int wave = tid >> 6, lane = tid & 63;
  int w_m = (wave >> 1) * 64, w_n = (wave & 1) * 64;
  int lm = lane & 15, lq = lane >> 4;

  f32x4 acc[4][4];
#pragma unroll
  for (int mi = 0; mi < 4; mi++)
#pragma unroll
    for (int ni = 0; ni < 4; ni++) acc[mi][ni] = (f32x4){0.f, 0.f, 0.f, 0.f};

  int sr = tid >> 2;
  int sc = (tid & 3) * 8;
  const _Float16* Ag0 = A + (size_t)(bm * 128 + sr) * K + sc;
  const _Float16* Ag1 = Ag0 + (size_t)64 * K;
  const _Float16* Bg0 = B + (size_t)(bn * 128 + sr) * K + sc;
  const _Float16* Bg1 = Bg0 + (size_t)64 * K;
  _Float16* lA0 = &As[wave * 16][0];
  _Float16* lA1 = &As[64 + wave * 16][0];
  _Float16* lB0 = &Bs[wave * 16][0];
  _Float16* lB1 = &Bs[64 + wave * 16][0];

  for (int k0 = 0; k0 < K; k0 += 32) {
    gload16(Ag0 + k0, lA0);
    gload16(Ag1 + k0, lA1);
    gload16(Bg0 + k0, lB0);
    gload16(Bg1 + k0, lB1);
    __syncthreads();

    f16x8 af[4], bf[4];
#pragma unroll
    for (int i = 0; i < 4; i++) af[i] = *(const f16x8*)&As[w_m + i * 16 + lm][lq * 8];
#pragma unroll
    for (int i = 0; i < 4; i++) bf[i] = *(const f16x8*)&Bs[w_n + i * 16 + lm][lq * 8];
#pragma unroll
    for (int mi = 0; mi < 4; mi++)
#pragma unroll
      for (int ni = 0; ni < 4; ni++)
        acc[mi][ni] =
            __builtin_amdgcn_mfma_f32_16x16x32_f16(af[mi], bf[ni], acc[mi][ni], 0, 0, 0);
    __syncthreads();
  }

  int rb = lq * 4;
#pragma unroll
  for (int mi = 0; mi < 4; mi++)
#pragma unroll
    for (int ni = 0; ni < 4; ni++) {
      size_t gr = (size_t)(bm * 128 + w_m + mi * 16 + rb);
      int gc = bn * 128 + w_n + ni * 16 + lm;
#pragma unroll
      for (int r = 0; r < 4; r++)
        C[(gr + r) * N + gc] = (OutT)acc[mi][ni][r];
    }
}

// ---------------- f16 2D transpose: out[C][R] = in[R][C] (R=8192, C=512) ----------------
__global__ __launch_bounds__(256) void transpose16(const _Float16* __restrict__ in,
                                                   _Float16* __restrict__ out) {
  __shared__ _Float16 Ts[64][72];
  const int R = 8192, Cc = 512;
  int tr = blockIdx.x * 64, tc = blockIdx.y * 64;
  int r0 = threadIdx.x >> 3, c8 = (threadIdx.x & 7) * 8;
#pragma unroll
  for (int i = 0; i < 2; i++) {
    int r = r0 + i * 32;
    *(f16x8*)&Ts[r][c8] = *(const f16x8*)&in[(size_t)(tr + r) * Cc + tc + c8];
  }
  __syncthreads();
#pragma unroll
  for (int i = 0; i < 2; i++) {
    int oc = r0 + i * 32;  // output-row offset within tile (= input col)
    f16x8 o;
#pragma unroll
    for (int j = 0; j < 8; j++) o[j] = Ts[c8 + j][oc];
    *(f16x8*)&out[(size_t)(tc + oc) * R + tr + c8] = o;
  }
}

// ---------------- RMSNorm + RoPE for Q (with gain) and K, one kernel ----------------
// one wave per row: Q rows = 131072 (bt*16+h), then K rows = 32768 (bt*4+n)
__global__ __launch_bounds__(256) void rmsrope_all(_Float16* __restrict__ qh,
                                                   _Float16* __restrict__ kh,
                                                   const float* __restrict__ gain) {
  int gw = blockIdx.x * 4 + (threadIdx.x >> 6);
  int lane = threadIdx.x & 63;
  _Float16* row;
  int t;
  float g = 1.0f;
  if (gw < 131072) {  // Q: gw = bt*16 + h
    int h = gw & 15;
    t = (gw >> 4) & 1023;
    row = qh + (size_t)gw * 128;
    g = gain[h];
  } else {            // K: gk = bt*4 + n
    int gk = gw - 131072;
    t = (gk >> 2) & 1023;
    row = kh + (size_t)gk * 128;
  }
  float x1 = (float)row[lane], x2 = (float)row[lane + 64];
  float ss = x1 * x1 + x2 * x2;
#pragma unroll
  for (int m = 1; m < 64; m <<= 1) ss += __shfl_xor(ss, m);
  float scale = rsqrtf(ss * (1.0f / 128.0f) + 1e-6f) * g;
  float inv = exp2f((float)lane * -0.2076205059304601f);  // 10000^(-lane/64)
  float ang = (float)t * inv;
  float c = cosf(ang), s = sinf(ang);
  row[lane]      = (_Float16)((x1 * c - x2 * s) * scale);
  row[lane + 64] = (_Float16)((x2 * c + x1 * s) * scale);
}

// ---------------- f16 MFMA flash attention (causal GQA) ----------------
// grid (T/64, H, B), qt reversed for load balance; 4 waves, wave owns 16 Q rows.
// q: [bt][16][128] f16; k: [bt][4][128] f16; vT: [512][8192] f16 ([(n,d)][(b,t)]);
// y: f16 [bt][16][128]
__global__ __launch_bounds__(256, 4) void attn_mfma(const _Float16* __restrict__ q,
                                                    const _Float16* __restrict__ k,
                                                    const _Float16* __restrict__ vT,
                                                    _Float16* __restrict__ y) {
  __shared__ _Float16 Ks[4][64][32];    // [k-chunk][s][32]  (dense, DMA-staged)
  __shared__ _Float16 VTs[2][128][32];  // [s-chunk][d][32]  (dense, DMA-staged)
  __shared__ _Float16 Ps[4][16][64];    // per-wave P, XOR-swizzled chunks
  int qt = (int)gridDim.x - 1 - blockIdx.x, h = blockIdx.y, b = blockIdx.z;
  int kvh = h >> 2;
  int tid = threadIdx.x, wave = tid >> 6, lane = tid & 63;
  int lm = lane & 15, lq = lane >> 4;

  // Q fragments (A-layout), registers
  const _Float16* qp =
      q + (size_t)((b * T_SEQ + qt * 64 + wave * 16 + lm) * 16 + h) * 128 + lq * 8;
  f16x8 qf[4];
#pragma unroll
  for (int i = 0; i < 4; i++) qf[i] = *(const f16x8*)(qp + i * 32);

  f32x4 O[8];
#pragma unroll
  for (int i = 0; i < 8; i++) O[i] = (f32x4){0.f, 0.f, 0.f, 0.f};
  float mrow[4] = {-1e30f, -1e30f, -1e30f, -1e30f};
  float lrow[4] = {0.f, 0.f, 0.f, 0.f};

  // staging pointers (per-lane global, wave-uniform LDS base)
  int srow = lane >> 2, scol = (lane & 3) * 8;
  const _Float16* kg =
      k + ((size_t)(b * T_SEQ + srow) * 4 + kvh) * 128 + wave * 32 + scol;
  const _Float16* vg =
      vT + (size_t)(kvh * 128 + (wave >> 1) * 64 + srow) * 8192 + b * T_SEQ +
      (wave & 1) * 32 + scol;

  const float SC = 0.08838834764831845f;
  int qrow_base = qt * 64 + wave * 16 + lq * 4;

  for (int s0 = 0; s0 <= qt * 64; s0 += 64) {
#pragma unroll
    for (int i = 0; i < 4; i++) {
      gload16(kg + (size_t)i * 8192, &Ks[wave][i * 16][0]);            // 16 s-rows
      gload16(vg + (size_t)i * 16 * 8192,
              &VTs[wave & 1][(wave >> 1) * 64 + i * 16][0]);           // 16 d-rows
    }
    kg += (size_t)64 * 512;  // next 64 s-rows
    vg += 64;                // next 64 t-cols
    __syncthreads();

    // S = Q K^T (16x64 per wave)
    f32x4 S[4];
#pragma unroll
    for (int ct = 0; ct < 4; ct++) {
      S[ct] = (f32x4){0.f, 0.f, 0.f, 0.f};
#pragma unroll
      for (int ks = 0; ks < 4; ks++) {
        f16x8 bf = *(const f16x8*)&Ks[ks][ct * 16 + lm][lq * 8];
        S[ct] = __builtin_amdgcn_mfma_f32_16x16x32_f16(qf[ks], bf, S[ct], 0, 0, 0);
      }
    }

    bool diag = (s0 == qt * 64);
    float p[4][4];
    float al[4];
#pragma unroll
    for (int r = 0; r < 4; r++) {
      int grow = qrow_base + r;
      float mx = -1e30f;
#pragma unroll
      for (int ct = 0; ct < 4; ct++) {
        float sv = S[ct][r] * SC;
        if (diag && (s0 + ct * 16 + lm > grow)) sv = -1e30f;
        p[r][ct] = sv;
        mx = fmaxf(mx, sv);
      }
#pragma unroll
      for (int m = 1; m < 16; m <<= 1) mx = fmaxf(mx, __shfl_xor(mx, m));
      float mn = fmaxf(mrow[r], mx);
      float a = __expf(mrow[r] - mn);
      mrow[r] = mn;
      float rs = 0.f;
#pragma unroll
      for (int ct = 0; ct < 4; ct++) {
        float pv = __expf(p[r][ct] - mn);
        p[r][ct] = pv;
        rs += pv;
      }
#pragma unroll
      for (int m = 1; m < 16; m <<= 1) rs += __shfl_xor(rs, m);
      lrow[r] = lrow[r] * a + rs;
      al[r] = a;
    }

    // P -> LDS, chunk-XOR swizzle: col_stored = ((col>>3)^(row&7))*8 + (col&7)
#pragma unroll
    for (int r = 0; r < 4; r++) {
      int row = lq * 4 + r;
#pragma unroll
      for (int ct = 0; ct < 4; ct++) {
        int cg = (ct * 2 + (lm >> 3)) ^ (row & 7);
        Ps[wave][row][cg * 8 + (lm & 7)] = (_Float16)p[r][ct];
      }
    }
#pragma unroll
    for (int ct = 0; ct < 8; ct++)
#pragma unroll
      for (int r = 0; r < 4; r++) O[ct][r] *= al[r];

    // O += P V  (A-frag of P from swizzled Ps; B-frag of V^T from VTs)
#pragma unroll
    for (int ks2 = 0; ks2 < 2; ks2++) {
      int cg = ((ks2 * 4 + lq) ^ (lm & 7));
      f16x8 af = *(const f16x8*)&Ps[wave][lm][cg * 8];
#pragma unroll
      for (int ct = 0; ct < 8; ct++) {
        f16x8 bf = *(const f16x8*)&VTs[ks2][ct * 16 + lm][lq * 8];
        O[ct] = __builtin_amdgcn_mfma_f32_16x16x32_f16(af, bf, O[ct], 0, 0, 0);
      }
    }
    __syncthreads();
  }

  float linv[4];
#pragma unroll
  for (int r = 0; r < 4; r++) linv[r] = 1.0f / lrow[r];
#pragma unroll
  for (int ct = 0; ct < 8; ct++)
#pragma unroll
    for (int r = 0; r < 4; r++)
      y[((size_t)(b * T_SEQ + qrow_base + r) * 16 + h) * 128 + ct * 16 + lm] =
          (_Float16)(O[ct][r] * linv[r]);
}

// ---------------- v-direction rejection (f16 in/out) ----------------
__global__ __launch_bounds__(256) void vreject(const _Float16* __restrict__ y,
                                               const _Float16* __restrict__ v,
                                               _Float16* __restrict__ yh) {
  int gw = blockIdx.x * 4 + (threadIdx.x >> 6);  // bt*4 + n
  int lane = threadIdx.x & 63;
  int bt = gw >> 2, n = gw & 3;
  const _Float16* vrow = v + (size_t)gw * 128;   // vh dense [bt][512]
  float v1 = (float)vrow[lane], v2 = (float)vrow[lane + 64];
  float ss = v1 * v1 + v2 * v2;
#pragma unroll
  for (int m = 1; m < 64; m <<= 1) ss += __shfl_xor(ss, m);
  float invn = 1.0f / (sqrtf(ss) + 1e-8f);
  float n1 = v1 * invn, n2 = v2 * invn;
  const _Float16* ybase = y + (size_t)bt * 2048 + n * 512;
  _Float16* obase = yh + (size_t)bt * 2048 + n * 512;
#pragma unroll
  for (int g = 0; g < 4; g++) {
    float y1 = (float)ybase[g * 128 + lane], y2 = (float)ybase[g * 128 + lane + 64];
    float d = y1 * n1 + y2 * n2;
#pragma unroll
    for (int m = 1; m < 64; m <<= 1) d += __shfl_xor(d, m);
    obase[g * 128 + lane]      = (_Float16)(y1 - d * n1);
    obase[g * 128 + lane + 64] = (_Float16)(y2 - d * n2);
  }
}

extern "C" void kernel_launch(void* const* d_in, const int* in_sizes, int n_in,
                              void* d_out, int out_size, void* d_ws, size_t ws_size,
                              hipStream_t stream) {
  const float* x    = (const float*)d_in[0];
  const float* Wq   = (const float*)d_in[1];
  const float* Wk   = (const float*)d_in[2];
  const float* Wv   = (const float*)d_in[3];
  const float* Wp   = (const float*)d_in[4];
  const float* gain = (const float*)d_in[5];
  float* out = (float*)d_out;

  // workspace layout (MB offsets)
  char* w = (char*)d_ws;
  _Float16* xh  = (_Float16*)(w + 0);                    // 32 MB
  _Float16* wqh = (_Float16*)(w + 32u * 1048576);        // 8 MB
  _Float16* wkh = (_Float16*)(w + 40u * 1048576);        // 2 MB
  _Float16* wvh = (_Float16*)(w + 42u * 1048576);        // 2 MB
  _Float16* wph = (_Float16*)(w + 44u * 1048576);        // 8 MB
  _Float16* qh  = (_Float16*)(w + 52u * 1048576);        // 32 MB
  _Float16* kh  = (_Float16*)(w + 84u * 1048576);        // 8 MB
  _Float16* vh  = (_Float16*)(w + 92u * 1048576);        // 8 MB
  _Float16* vTg = (_Float16*)(w + 100u * 1048576);       // 8 MB
  _Float16* ya  = (_Float16*)(w + 108u * 1048576);       // 32 MB
  _Float16* yh2 = xh;  // xh dead after QKV GEMMs

  // 1) all converts (x, Wq, Wk, Wv, Wp) -> f16
  convert_all<<<13312, 256, 0, stream>>>(x, Wq, Wk, Wv, Wp, xh, wqh, wkh, wvh, wph);

  // 2) QKV projections (MFMA, f16 out)
  gemm128<_Float16><<<dim3(64, 16), 256, 0, stream>>>(xh, wqh, qh, 2048, 2048);
  gemm128<_Float16><<<dim3(64, 4), 256, 0, stream>>>(xh, wkh, kh, 2048, 512);
  gemm128<_Float16><<<dim3(64, 4), 256, 0, stream>>>(xh, wvh, vh, 2048, 512);

  // 3) V transpose ([8192][512] -> [512][8192]); RMSNorm+RoPE on Q and K
  transpose16<<<dim3(128, 8), 256, 0, stream>>>(vh, vTg);
  // 131072 Q rows + 32768 K rows = 163840 waves = 40960 blocks
  rmsrope_all<<<40960, 256, 0, stream>>>(qh, kh, gain);

  // 4) causal GQA MFMA flash attention -> ya (f16)
  attn_mfma<<<dim3(16, 16, 8), 256, 0, stream>>>(qh, kh, vTg, ya);

  // 5) reject v-hat component
  vreject<<<8192, 256, 0, stream>>>(ya, vh, yh2);

  // 6) output projection -> final out (f32)
  gemm128<float><<<dim3(64, 16), 256, 0, stream>>>(yh2, wph, out, 2048, 2048);
}

// Round 6
// 600.591 us; speedup vs baseline: 4.2710x; 1.0773x over previous
//
#include <hip/hip_runtime.h>
#include <stdint.h>

// B=8, T=1024, DIM=2048, H=16, NKV=4, HD=128, G=4
#define T_SEQ 1024

typedef _Float16 f16x8 __attribute__((ext_vector_type(8)));
typedef float f32x4 __attribute__((ext_vector_type(4)));

typedef __attribute__((address_space(1))) const uint8_t* gptr_t;
typedef __attribute__((address_space(3))) uint8_t* lptr_t;

__device__ __forceinline__ void gload16(const _Float16* g, _Float16* l) {
  // async global->LDS DMA, 16B/lane; LDS dest = wave-uniform base + lane*16
  __builtin_amdgcn_global_load_lds((gptr_t)g, (lptr_t)l, 16, 0, 0);
}

// ---------------- all five fp32->fp16 converts in one kernel ----------------
// wk goes to wkv[0:512], wv to wkv[512:1024] (fused KV weight)
__global__ __launch_bounds__(256) void convert_all(
    const float* __restrict__ x, const float* __restrict__ Wq,
    const float* __restrict__ Wk, const float* __restrict__ Wv,
    const float* __restrict__ Wp, _Float16* __restrict__ xh,
    _Float16* __restrict__ wqh, _Float16* __restrict__ wkh,
    _Float16* __restrict__ wvh, _Float16* __restrict__ wph) {
  int i = blockIdx.x * 256 + threadIdx.x;  // vec8 index, total 3407872
  const float* in;
  _Float16* out;
  int base;
  if (i < 2097152)      { in = x;  out = xh;  base = 0; }
  else if (i < 2621440) { in = Wq; out = wqh; base = 2097152; }
  else if (i < 2752512) { in = Wk; out = wkh; base = 2621440; }
  else if (i < 2883584) { in = Wv; out = wvh; base = 2752512; }
  else                  { in = Wp; out = wph; base = 2883584; }
  int j = i - base;
  const float4* p = (const float4*)in + (size_t)j * 2;
  float4 a = p[0], b = p[1];
  f16x8 o;
  o[0] = (_Float16)a.x; o[1] = (_Float16)a.y; o[2] = (_Float16)a.z; o[3] = (_Float16)a.w;
  o[4] = (_Float16)b.x; o[5] = (_Float16)b.y; o[6] = (_Float16)b.z; o[7] = (_Float16)b.w;
  ((f16x8*)out)[j] = o;
}

// ---------------- m97-style f16 MFMA GEMM: C[M,N] = A[M,K] @ B[N,K]^T ----------------
template <typename OutT>
__global__ __launch_bounds__(256) void gemm128(const _Float16* __restrict__ A,
                                               const _Float16* __restrict__ B,
                                               OutT* __restrict__ C,
                                               int K, int N) {
  __shared__ _Float16 As[128][32];  // dense: global_load_lds lane order
  __shared__ _Float16 Bs[128][32];
  int tid = threadIdx.x;
  int bm = blockIdx.x, bn = blockIdx.y;
  int wave = tid >> 6, lane = tid & 63;
  int w_m = (wave >> 1) * 64, w_n = (wave & 1) * 64;
  int lm = lane & 15, lq = lane >> 4;

  f32x4 acc[4][4];
#pragma unroll
  for (int mi = 0; mi < 4; mi++)
#pragma unroll
    for (int ni = 0; ni < 4; ni++) acc[mi][ni] = (f32x4){0.f, 0.f, 0.f, 0.f};

  int sr = tid >> 2;
  int sc = (tid & 3) * 8;
  const _Float16* Ag0 = A + (size_t)(bm * 128 + sr) * K + sc;
  const _Float16* Ag1 = Ag0 + (size_t)64 * K;
  const _Float16* Bg0 = B + (size_t)(bn * 128 + sr) * K + sc;
  const _Float16* Bg1 = Bg0 + (size_t)64 * K;
  _Float16* lA0 = &As[wave * 16][0];
  _Float16* lA1 = &As[64 + wave * 16][0];
  _Float16* lB0 = &Bs[wave * 16][0];
  _Float16* lB1 = &Bs[64 + wave * 16][0];

  for (int k0 = 0; k0 < K; k0 += 32) {
    gload16(Ag0 + k0, lA0);
    gload16(Ag1 + k0, lA1);
    gload16(Bg0 + k0, lB0);
    gload16(Bg1 + k0, lB1);
    __syncthreads();

    f16x8 af[4], bf[4];
#pragma unroll
    for (int i = 0; i < 4; i++) af[i] = *(const f16x8*)&As[w_m + i * 16 + lm][lq * 8];
#pragma unroll
    for (int i = 0; i < 4; i++) bf[i] = *(const f16x8*)&Bs[w_n + i * 16 + lm][lq * 8];
#pragma unroll
    for (int mi = 0; mi < 4; mi++)
#pragma unroll
      for (int ni = 0; ni < 4; ni++)
        acc[mi][ni] =
            __builtin_amdgcn_mfma_f32_16x16x32_f16(af[mi], bf[ni], acc[mi][ni], 0, 0, 0);
    __syncthreads();
  }

  int rb = lq * 4;
#pragma unroll
  for (int mi = 0; mi < 4; mi++)
#pragma unroll
    for (int ni = 0; ni < 4; ni++) {
      size_t gr = (size_t)(bm * 128 + w_m + mi * 16 + rb);
      int gc = bn * 128 + w_n + ni * 16 + lm;
#pragma unroll
      for (int r = 0; r < 4; r++)
        C[(gr + r) * N + gc] = (OutT)acc[mi][ni][r];
    }
}

// ---------------- f16 transpose of V half of kvb: out[512][8192] ----------------
// in = kvb + 512 (row stride 1024); out dense [col][8192]
__global__ __launch_bounds__(256) void transpose16(const _Float16* __restrict__ in,
                                                   _Float16* __restrict__ out) {
  __shared__ _Float16 Ts[64][72];
  int tr = blockIdx.x * 64, tc = blockIdx.y * 64;
  int r0 = threadIdx.x >> 3, c8 = (threadIdx.x & 7) * 8;
#pragma unroll
  for (int i = 0; i < 2; i++) {
    int r = r0 + i * 32;
    *(f16x8*)&Ts[r][c8] = *(const f16x8*)&in[(size_t)(tr + r) * 1024 + tc + c8];
  }
  __syncthreads();
#pragma unroll
  for (int i = 0; i < 2; i++) {
    int oc = r0 + i * 32;
    f16x8 o;
#pragma unroll
    for (int j = 0; j < 8; j++) o[j] = Ts[c8 + j][oc];
    *(f16x8*)&out[(size_t)(tc + oc) * 8192 + tr + c8] = o;
  }
}

// ---------------- RMSNorm + RoPE for Q (with gain) and K, one kernel ----------------
// Q rows = 131072 (bt*16+h, dense 128); K rows = 32768 (bt*4+n, in kvb stride 1024)
__global__ __launch_bounds__(256) void rmsrope_all(_Float16* __restrict__ qh,
                                                   _Float16* __restrict__ kvb,
                                                   const float* __restrict__ gain) {
  int gw = blockIdx.x * 4 + (threadIdx.x >> 6);
  int lane = threadIdx.x & 63;
  _Float16* row;
  int t;
  float g = 1.0f;
  if (gw < 131072) {  // Q: gw = bt*16 + h
    int h = gw & 15;
    t = (gw >> 4) & 1023;
    row = qh + (size_t)gw * 128;
    g = gain[h];
  } else {            // K: gk = bt*4 + n -> kvb[bt][n*128..]
    int gk = gw - 131072;
    t = (gk >> 2) & 1023;
    row = kvb + (size_t)(gk >> 2) * 1024 + (gk & 3) * 128;
  }
  float x1 = (float)row[lane], x2 = (float)row[lane + 64];
  float ss = x1 * x1 + x2 * x2;
#pragma unroll
  for (int m = 1; m < 64; m <<= 1) ss += __shfl_xor(ss, m);
  float scale = rsqrtf(ss * (1.0f / 128.0f) + 1e-6f) * g;
  float inv = exp2f((float)lane * -0.2076205059304601f);  // 10000^(-lane/64)
  float ang = (float)t * inv;
  float c = cosf(ang), s = sinf(ang);
  row[lane]      = (_Float16)((x1 * c - x2 * s) * scale);
  row[lane + 64] = (_Float16)((x2 * c + x1 * s) * scale);
}

// ---------------- f16 MFMA flash attention (causal GQA), Q-tile 128 ----------------
// grid (T/128, H, B), qt reversed; 4 waves; wave owns 32 Q rows (2 m-tiles).
// q: [bt][16][128]; k: kvb [bt][1024] (K at cols 0..511, n*128+d);
// vT: [512][8192] ([(n,d)][(b,t)]); y: f16 [bt][16][128]
__global__ __launch_bounds__(256, 2) void attn_mfma(const _Float16* __restrict__ q,
                                                    const _Float16* __restrict__ k,
                                                    const _Float16* __restrict__ vT,
                                                    _Float16* __restrict__ y) {
  __shared__ _Float16 Ks[4][64][32];    // [d-chunk][s][32] (DMA-staged)
  __shared__ _Float16 VTs[2][128][32];  // [s-chunk][d][32] (DMA-staged)
  __shared__ _Float16 Ps[4][32][64];    // per-wave P (32 rows), XOR-swizzled
  int qt = (int)gridDim.x - 1 - blockIdx.x, h = blockIdx.y, b = blockIdx.z;
  int kvh = h >> 2;
  int tid = threadIdx.x, wave = tid >> 6, lane = tid & 63;
  int lm = lane & 15, lq = lane >> 4;

  // Q fragments: 2 m-tiles x 4 k-chunks, registers
  f16x8 qf[2][4];
#pragma unroll
  for (int mt = 0; mt < 2; mt++) {
    const _Float16* qp =
        q + ((size_t)((b * T_SEQ + qt * 128 + wave * 32 + mt * 16 + lm) * 16 + h)) * 128 +
        lq * 8;
#pragma unroll
    for (int ks = 0; ks < 4; ks++) qf[mt][ks] = *(const f16x8*)(qp + ks * 32);
  }

  f32x4 O[2][8];
#pragma unroll
  for (int mt = 0; mt < 2; mt++)
#pragma unroll
    for (int i = 0; i < 8; i++) O[mt][i] = (f32x4){0.f, 0.f, 0.f, 0.f};
  float mrow[2][4], lrow[2][4];
#pragma unroll
  for (int mt = 0; mt < 2; mt++)
#pragma unroll
    for (int r = 0; r < 4; r++) { mrow[mt][r] = -1e30f; lrow[mt][r] = 0.f; }

  int srow = lane >> 2, scol = (lane & 3) * 8;
  const _Float16* kg =
      k + (size_t)(b * T_SEQ + srow) * 1024 + kvh * 128 + wave * 32 + scol;
  const _Float16* vg =
      vT + (size_t)(kvh * 128 + (wave >> 1) * 64 + srow) * 8192 + b * T_SEQ +
      (wave & 1) * 32 + scol;

  const float SC = 0.08838834764831845f;
  int wrow = qt * 128 + wave * 32;  // wave's first Q row

  int smax = qt * 128 + 128;
  for (int s0 = 0; s0 < smax; s0 += 64) {
#pragma unroll
    for (int i = 0; i < 4; i++) {
      gload16(kg + (size_t)i * 16 * 1024, &Ks[wave][i * 16][0]);
      gload16(vg + (size_t)i * 16 * 8192, &VTs[wave & 1][(wave >> 1) * 64 + i * 16][0]);
    }
    kg += (size_t)64 * 1024;
    vg += 64;
    __syncthreads();

    // S = Q K^T: 2 m-tiles x 64 cols per wave; B-frags shared across m-tiles
    f32x4 S[2][4];
#pragma unroll
    for (int mt = 0; mt < 2; mt++)
#pragma unroll
      for (int ct = 0; ct < 4; ct++) S[mt][ct] = (f32x4){0.f, 0.f, 0.f, 0.f};
#pragma unroll
    for (int ct = 0; ct < 4; ct++)
#pragma unroll
      for (int ks = 0; ks < 4; ks++) {
        f16x8 bf = *(const f16x8*)&Ks[ks][ct * 16 + lm][lq * 8];
        S[0][ct] = __builtin_amdgcn_mfma_f32_16x16x32_f16(qf[0][ks], bf, S[0][ct], 0, 0, 0);
        S[1][ct] = __builtin_amdgcn_mfma_f32_16x16x32_f16(qf[1][ks], bf, S[1][ct], 0, 0, 0);
      }

    // online softmax; C rows = lq*4+r (within m-tile), cols = ct*16+lm
    float p[2][4][4], al[2][4];
#pragma unroll
    for (int mt = 0; mt < 2; mt++) {
      bool need_mask = (s0 + 63 > wrow + mt * 16);  // wave-uniform
#pragma unroll
      for (int r = 0; r < 4; r++) {
        int grow = wrow + mt * 16 + lq * 4 + r;
        float mx = -1e30f;
#pragma unroll
        for (int ct = 0; ct < 4; ct++) {
          float sv = S[mt][ct][r] * SC;
          if (need_mask && (s0 + ct * 16 + lm > grow)) sv = -1e30f;
          p[mt][r][ct] = sv;
          mx = fmaxf(mx, sv);
        }
#pragma unroll
        for (int m = 1; m < 16; m <<= 1) mx = fmaxf(mx, __shfl_xor(mx, m));
        float mn = fmaxf(mrow[mt][r], mx);
        float a = __expf(mrow[mt][r] - mn);
        mrow[mt][r] = mn;
        float rs = 0.f;
#pragma unroll
        for (int ct = 0; ct < 4; ct++) {
          float pv = __expf(p[mt][r][ct] - mn);
          p[mt][r][ct] = pv;
          rs += pv;
        }
#pragma unroll
        for (int m = 1; m < 16; m <<= 1) rs += __shfl_xor(rs, m);
        lrow[mt][r] = lrow[mt][r] * a + rs;
        al[mt][r] = a;
      }
    }

    // P -> LDS (XOR-swizzled: cg = (col>>3) ^ (row&7)), rescale O
#pragma unroll
    for (int mt = 0; mt < 2; mt++)
#pragma unroll
      for (int r = 0; r < 4; r++) {
        int prow = mt * 16 + lq * 4 + r;
#pragma unroll
        for (int ct = 0; ct < 4; ct++) {
          int cg = (ct * 2 + (lm >> 3)) ^ (prow & 7);
          Ps[wave][prow][cg * 8 + (lm & 7)] = (_Float16)p[mt][r][ct];
        }
      }
#pragma unroll
    for (int mt = 0; mt < 2; mt++)
#pragma unroll
      for (int ct = 0; ct < 8; ct++)
#pragma unroll
        for (int r = 0; r < 4; r++) O[mt][ct][r] *= al[mt][r];

    // O += P V (A-frags from swizzled Ps, B-frags shared across m-tiles)
#pragma unroll
    for (int ks2 = 0; ks2 < 2; ks2++) {
      f16x8 af[2];
#pragma unroll
      for (int mt = 0; mt < 2; mt++) {
        int prow = mt * 16 + lm;
        int cg = (ks2 * 4 + lq) ^ (prow & 7);
        af[mt] = *(const f16x8*)&Ps[wave][prow][cg * 8];
      }
#pragma unroll
      for (int ct = 0; ct < 8; ct++) {
        f16x8 bf = *(const f16x8*)&VTs[ks2][ct * 16 + lm][lq * 8];
        O[0][ct] = __builtin_amdgcn_mfma_f32_16x16x32_f16(af[0], bf, O[0][ct], 0, 0, 0);
        O[1][ct] = __builtin_amdgcn_mfma_f32_16x16x32_f16(af[1], bf, O[1][ct], 0, 0, 0);
      }
    }
    __syncthreads();
  }

#pragma unroll
  for (int mt = 0; mt < 2; mt++) {
    float linv[4];
#pragma unroll
    for (int r = 0; r < 4; r++) linv[r] = 1.0f / lrow[mt][r];
    int qrow_base = wrow + mt * 16 + lq * 4;
#pragma unroll
    for (int ct = 0; ct < 8; ct++)
#pragma unroll
      for (int r = 0; r < 4; r++)
        y[((size_t)(b * T_SEQ + qrow_base + r) * 16 + h) * 128 + ct * 16 + lm] =
            (_Float16)(O[mt][ct][r] * linv[r]);
  }
}

// ---------------- v-direction rejection (f16 in/out) ----------------
__global__ __launch_bounds__(256) void vreject(const _Float16* __restrict__ y,
                                               const _Float16* __restrict__ kvb,
                                               _Float16* __restrict__ yh) {
  int gw = blockIdx.x * 4 + (threadIdx.x >> 6);  // bt*4 + n
  int lane = threadIdx.x & 63;
  int bt = gw >> 2, n = gw & 3;
  const _Float16* vrow = kvb + (size_t)bt * 1024 + 512 + n * 128;
  float v1 = (float)vrow[lane], v2 = (float)vrow[lane + 64];
  float ss = v1 * v1 + v2 * v2;
#pragma unroll
  for (int m = 1; m < 64; m <<= 1) ss += __shfl_xor(ss, m);
  float invn = 1.0f / (sqrtf(ss) + 1e-8f);
  float n1 = v1 * invn, n2 = v2 * invn;
  const _Float16* ybase = y + (size_t)bt * 2048 + n * 512;
  _Float16* obase = yh + (size_t)bt * 2048 + n * 512;
#pragma unroll
  for (int g = 0; g < 4; g++) {
    float y1 = (float)ybase[g * 128 + lane], y2 = (float)ybase[g * 128 + lane + 64];
    float d = y1 * n1 + y2 * n2;
#pragma unroll
    for (int m = 1; m < 64; m <<= 1) d += __shfl_xor(d, m);
    obase[g * 128 + lane]      = (_Float16)(y1 - d * n1);
    obase[g * 128 + lane + 64] = (_Float16)(y2 - d * n2);
  }
}

extern "C" void kernel_launch(void* const* d_in, const int* in_sizes, int n_in,
                              void* d_out, int out_size, void* d_ws, size_t ws_size,
                              hipStream_t stream) {
  const float* x    = (const float*)d_in[0];
  const float* Wq   = (const float*)d_in[1];
  const float* Wk   = (const float*)d_in[2];
  const float* Wv   = (const float*)d_in[3];
  const float* Wp   = (const float*)d_in[4];
  const float* gain = (const float*)d_in[5];
  float* out = (float*)d_out;

  // workspace layout (MB offsets)
  char* w = (char*)d_ws;
  _Float16* xh   = (_Float16*)(w + 0);                 // 32 MB
  _Float16* wqh  = (_Float16*)(w + 32u * 1048576);     // 8 MB
  _Float16* wkvh = (_Float16*)(w + 40u * 1048576);     // 4 MB (K rows 0..511, V rows 512..1023)
  _Float16* wph  = (_Float16*)(w + 44u * 1048576);     // 8 MB
  _Float16* qh   = (_Float16*)(w + 52u * 1048576);     // 32 MB
  _Float16* kvb  = (_Float16*)(w + 84u * 1048576);     // 16 MB  [bt][K 512 | V 512]
  _Float16* vTg  = (_Float16*)(w + 100u * 1048576);    // 8 MB   [512][8192]
  _Float16* ya   = (_Float16*)(w + 108u * 1048576);    // 32 MB
  _Float16* yh2  = xh;  // xh dead after QKV GEMMs

  // 1) converts -> f16 (Wk into wkvh[0:512], Wv into wkvh[512:1024])
  convert_all<<<13312, 256, 0, stream>>>(x, Wq, Wk, Wv, Wp, xh, wqh,
                                         wkvh, wkvh + (size_t)512 * 2048, wph);

  // 2) projections: Q (N=2048) and fused KV (N=1024)
  gemm128<_Float16><<<dim3(64, 16), 256, 0, stream>>>(xh, wqh, qh, 2048, 2048);
  gemm128<_Float16><<<dim3(64, 8), 256, 0, stream>>>(xh, wkvh, kvb, 2048, 1024);

  // 3) V transpose (kvb V half -> vTg [512][8192]); RMSNorm+RoPE on Q and K
  transpose16<<<dim3(128, 8), 256, 0, stream>>>(kvb + 512, vTg);
  rmsrope_all<<<40960, 256, 0, stream>>>(qh, kvb, gain);  // 163840 waves

  // 4) causal GQA MFMA flash attention (Q-tile 128) -> ya (f16)
  attn_mfma<<<dim3(8, 16, 8), 256, 0, stream>>>(qh, kvb, vTg, ya);

  // 5) reject v-hat component
  vreject<<<8192, 256, 0, stream>>>(ya, kvb, yh2);

  // 6) output projection -> final out (f32)
  gemm128<float><<<dim3(64, 16), 256, 0, stream>>>(yh2, wph, out, 2048, 2048);
}